// Round 6
// baseline (2888.816 us; speedup 1.0000x reference)
//
#include <hip/hip_runtime.h>

#define B_ 8
#define N_ 32768
#define S_ 1024
#define C_ 96
#define T_ 512             // ONE block per batch: 8 waves on one CU, LDS-only sync
#define W_ (T_ / 64)       // 8 waves per block
#define PPT (N_ / T_)      // 64 points per thread
#define NQ (PPT / 4)       // 16 quads of 4 points per thread
#define RQ 12              // quads with coords in REGISTERS (j = 0..47)
#define SQ (NQ - RQ)       // 4 quads with coords spilled to LDS (j = 48..63)

typedef float f4v __attribute__((ext_vector_type(4)));
typedef unsigned long long u64;
typedef unsigned int u32;

// Round 6: round 5's 256 KB/step of Dl LDS traffic was pure PRIVATE spill
// (thread t is the only reader/writer of Dl[*][t]) -> move D into registers
// and spill read-only COORDS instead (a D float costs 2 LDS ops/step, a
// coord float costs 1). Per thread: Dr[64] in regs (static unroll only),
// coords of quads 0..11 in regs (144), quads 12..15 in LDS (96 KB, 12 b128
// reads/step, 1-ahead prefetch, consumed LAST -> ascending-j scan order and
// all tie-breaks preserved). Removes ~2700 cy/step of DS traffic and the
// 120-cy post-loop Dl reload. Distance expression ((dx*dx+dy*dy)+dz*dz,
// contract off), DPP two-phase wave reduce, and cross-wave u64 exchange are
// verbatim from the proven round-5 kernel -> identical winners, absmax 0.
// Register budget @ 2 waves/SIMD = 256: state 208 + working ~25 + prefetch
// 12 ~= 245; overflow spills to AGPR (move tax), not scratch. Diagnostic:
// FETCH/WRITE ballooning would mean scratch spill.

// d_out layout (float32, concatenated):
//   [0, B*S*3)                      new_xyz  (B,S,3)
//   [B*S*3, B*S*3+B*C*S)            new_fea  (B,C,S)
//   [B*S*3+B*C*S, +B*S)             indices  (B,S) as float

// 6-step wave64 DPP reduce (valid-source lanes combine, invalid keep old):
#define DPP_FMAX(x, ctrl)                                                   \
  x = fmaxf(x, __int_as_float(__builtin_amdgcn_update_dpp(                  \
          __float_as_int(x), __float_as_int(x), ctrl, 0xf, 0xf, false)))
#define DPP_UMIN(c, ctrl)                                                   \
  {                                                                         \
    const u32 o_ = (u32)__builtin_amdgcn_update_dpp(                        \
        (int)c, (int)c, ctrl, 0xf, 0xf, false);                             \
    c = (o_ < c) ? o_ : c;                                                  \
  }

__global__ __launch_bounds__(T_)
__attribute__((amdgpu_waves_per_eu(2, 2)))   // 8 waves = 2/SIMD -> 256-reg budget
void fps_kernel(
    const float* __restrict__ xyz,   // (B, N, 3)
    float* __restrict__ out)
{
#pragma clang fp contract(off)
  const int b    = blockIdx.x;       // one block per batch
  const int t    = threadIdx.x;
  const int lane = t & 63;
  const int w    = t >> 6;
  const float* xb = xyz + (size_t)b * N_ * 3;

  float* out_xyz = out;
  float* out_idx = out + (size_t)B_*S_*3 + (size_t)B_*C_*S_;

  __shared__ f4v CS[SQ][3][T_];      // 96 KB spilled coords (x,y,z per quad)
  __shared__ u64 red[2][W_];         // per-wave winner keys, parity dbuf

  // Reg-resident coords for j = 0..4*RQ-1 (point g = j*T_ + t; ascending j
  // -> first-max scan == smallest global index).
  float CXr[4*RQ], CYr[4*RQ], CZr[4*RQ];
  float Dr[PPT];                     // running min-dists, ALL in registers
  #pragma unroll
  for (int j = 0; j < 4*RQ; ++j) {
    const int g = j * T_ + t;
    CXr[j] = xb[g*3+0];
    CYr[j] = xb[g*3+1];
    CZr[j] = xb[g*3+2];
  }
  #pragma unroll
  for (int j = 0; j < 4*RQ; ++j) {
    asm volatile("" : "+v"(CXr[j]), "+v"(CYr[j]), "+v"(CZr[j]));
  }
  // Spilled coords for j = 4*RQ..63 into LDS (private column t).
  #pragma unroll
  for (int q = 0; q < SQ; ++q) {
    f4v vx, vy, vz;
    #pragma unroll
    for (int e = 0; e < 4; ++e) {
      const int g = ((RQ + q) * 4 + e) * T_ + t;
      vx[e] = xb[g*3+0];
      vy[e] = xb[g*3+1];
      vz[e] = xb[g*3+2];
    }
    CS[q][0][t] = vx; CS[q][1][t] = vy; CS[q][2][t] = vz;
  }
  #pragma unroll
  for (int j = 0; j < PPT; ++j) Dr[j] = 1e10f;
  __syncthreads();

  int cur = 0;
  for (int s = 0; s < S_; ++s) {
    const int cu = __builtin_amdgcn_readfirstlane(cur);   // uniform -> scalar loads
    const float cx = xb[cu*3+0];
    const float cy = xb[cu*3+1];
    const float cz = xb[cu*3+2];
    if (t == 0) {
      out_idx[(size_t)b*S_ + s] = (float)cu;
      float* o = out_xyz + ((size_t)b*S_ + s)*3;
      o[0] = cx; o[1] = cy; o[2] = cz;
    }

    // Exact IEEE ((dx*dx + dy*dy) + dz*dz), no contraction (verbatim).
    // Per-point: min into Dr (regs). Per-quad: max + first-quad strict->
    // select that also latches the quad's 4 nd values for element resolve.
    float bv = -1.0f;
    int   bq = 0;
    float nw0 = 0.f, nw1 = 0.f, nw2 = 0.f, nw3 = 0.f;

    #define PT(jj, xx, yy, zz, ndv)                                        \
      {                                                                    \
        const float dx = (xx) - cx;                                        \
        const float dy = (yy) - cy;                                        \
        const float dz = (zz) - cz;                                        \
        const float dd = (dx*dx + dy*dy) + dz*dz;                          \
        ndv = fminf(Dr[jj], dd);                                           \
        Dr[jj] = ndv;                                                      \
      }
    #define QSEL(qc, n0, n1, n2, n3)                                       \
      {                                                                    \
        const float qm = fmaxf(fmaxf(n0, n1), fmaxf(n2, n3));              \
        if (qm > bv) {                                                     \
          bv = qm; bq = (qc);                                              \
          nw0 = n0; nw1 = n1; nw2 = n2; nw3 = n3;                          \
        }                                                                  \
      }

    // Prefetch first spilled quad; it is consumed after all reg quads.
    f4v px = CS[0][0][t], py = CS[0][1][t], pz = CS[0][2][t];

    #pragma unroll
    for (int q = 0; q < RQ; ++q) {
      float n0, n1, n2, n3;
      PT(4*q+0, CXr[4*q+0], CYr[4*q+0], CZr[4*q+0], n0);
      PT(4*q+1, CXr[4*q+1], CYr[4*q+1], CZr[4*q+1], n1);
      PT(4*q+2, CXr[4*q+2], CYr[4*q+2], CZr[4*q+2], n2);
      PT(4*q+3, CXr[4*q+3], CYr[4*q+3], CZr[4*q+3], n3);
      QSEL(q, n0, n1, n2, n3);
    }
    #pragma unroll
    for (int q = 0; q < SQ; ++q) {
      const f4v qx = px, qy = py, qz = pz;
      if (q + 1 < SQ) {             // 1-ahead rolling prefetch
        px = CS[q+1][0][t]; py = CS[q+1][1][t]; pz = CS[q+1][2][t];
      }
      float n0, n1, n2, n3;
      PT((RQ+q)*4+0, qx[0], qy[0], qz[0], n0);
      PT((RQ+q)*4+1, qx[1], qy[1], qz[1], n1);
      PT((RQ+q)*4+2, qx[2], qy[2], qz[2], n2);
      PT((RQ+q)*4+3, qx[3], qy[3], qz[3], n3);
      QSEL(RQ+q, n0, n1, n2, n3);
    }
    #undef PT
    #undef QSEL

    // Element within winning quad from latched nd regs (fmax returns its
    // operands bitwise -> equality holds). Descending priority == first
    // (smallest) matching element.
    int e = 3;
    if (nw2 == bv) e = 2;
    if (nw1 == bv) e = 1;
    if (nw0 == bv) e = 0;
    const int bj = (bq << 2) + e;    // per-thread point ordinal 0..63
    const int bg = (bj << 9) + t;    // global point index (T_ == 512)

    // Wave reduce via DPP (no LDS): value max -> lane 63; then min global
    // index among lanes holding the max (verbatim from round 5).
    float xv = bv;
    DPP_FMAX(xv, 0x111);             // row_shr:1
    DPP_FMAX(xv, 0x112);             // row_shr:2
    DPP_FMAX(xv, 0x114);             // row_shr:4
    DPP_FMAX(xv, 0x118);             // row_shr:8
    DPP_FMAX(xv, 0x142);             // row_bcast:15
    DPP_FMAX(xv, 0x143);             // row_bcast:31
    const float vmax = __int_as_float(
        __builtin_amdgcn_readlane(__float_as_int(xv), 63));
    u32 c = (bv == vmax) ? (u32)bg : 0xFFFFFFFFu;
    DPP_UMIN(c, 0x111);
    DPP_UMIN(c, 0x112);
    DPP_UMIN(c, 0x114);
    DPP_UMIN(c, 0x118);
    DPP_UMIN(c, 0x142);
    DPP_UMIN(c, 0x143);
    const u32 widx = (u32)__builtin_amdgcn_readlane((int)c, 63);

    // Cross-wave reduce: one LDS slot per wave, ONE barrier, local combine.
    // Key = (bits(vmax)<<32) | ~idx : u64-max == (max dist, min idx).
    const u64 wkey = ((u64)__float_as_uint(vmax) << 32) | (u32)(~widx);
    if (lane == 0) red[s & 1][w] = wkey;
    __syncthreads();
    u64 k = red[s & 1][lane & (W_ - 1)];       // 8 keys, broadcast across groups
    #pragma unroll
    for (int off = W_ / 2; off > 0; off >>= 1) {   // reduce within 8-lane groups
      const u64 ok = __shfl_xor(k, off);
      if (ok > k) k = ok;
    }
    cur = (int)(u32)(~(u32)k);                 // decode winner index
  }
}

__global__ void gather_fea_kernel(
    const float* __restrict__ feat,   // (B, C, N)
    const float* __restrict__ idxf,   // (B, S) float indices (in d_out)
    float* __restrict__ out_fea)      // (B, C, S)
{
  const int t = blockIdx.x * blockDim.x + threadIdx.x;
  if (t >= B_ * C_ * S_) return;
  const int s  = t & (S_ - 1);
  const int bc = t >> 10;           // S_ == 1024
  const int c  = bc % C_;
  const int b  = bc / C_;
  const int idx = (int)idxf[(size_t)b * S_ + s];
  out_fea[t] = feat[((size_t)b * C_ + c) * (size_t)N_ + idx];
}

extern "C" void kernel_launch(void* const* d_in, const int* in_sizes, int n_in,
                              void* d_out, int out_size, void* d_ws, size_t ws_size,
                              hipStream_t stream) {
  const float* xyz  = (const float*)d_in[0];   // (B,N,3)
  const float* feat = (const float*)d_in[1];   // (B,C,N)
  float* out = (float*)d_out;

  float* out_fea = out + (size_t)B_ * S_ * 3;
  float* out_idx = out + (size_t)B_ * S_ * 3 + (size_t)B_ * C_ * S_;
  (void)d_ws; (void)ws_size; (void)in_sizes; (void)n_in; (void)out_size;

  fps_kernel<<<B_, T_, 0, stream>>>(xyz, out);

  const int total = B_ * C_ * S_;
  gather_fea_kernel<<<(total + 255) / 256, 256, 0, stream>>>(feat, out_idx, out_fea);
}

// Round 7
// 2595.758 us; speedup vs baseline: 1.1129x; 1.1129x over previous
//
#include <hip/hip_runtime.h>

#define B_ 8
#define N_ 32768
#define S_ 1024
#define C_ 96
#define T_ 512             // ONE block per batch: 8 waves on one CU, LDS-only sync
#define W_ (T_ / 64)       // 8 waves per block
#define PPT (N_ / T_)      // 64 points per thread
#define NQ (PPT / 4)       // 16 quads of 4 points per thread
#define RQP 12             // quads with coords in registers (j = 0..47)
#define LQP (NQ - RQP)     // 4 quads with coords in LDS (j = 48..63)

typedef float f2v __attribute__((ext_vector_type(2)));
typedef float f4v __attribute__((ext_vector_type(4)));
typedef unsigned long long u64;
typedef unsigned int u32;

// Round 7: round 6 showed the active CU's VALU at 91% issue occupancy --
// the wall is VALU instructions, not DS (idle) or memory. Three levers,
// all semantics-preserving:
//  1. packed f2v distance chain (round-5 form): v_pk_*_f32 does 2 FP32
//     ops/instr; per-element IEEE bits identical to scalar (contract off).
//  2. balanced residency: D (2 touches/step) in regs (f2v Dr[32]); coords
//     12 quads in regs + 4 quads in LDS (read-only, 12 b128/thread/step on
//     the idle DS pipe, 1-ahead prefetch, consumed LAST -> ascending-j scan
//     order and tie-breaks preserved). Total reg state ~245 <= 256 unified
//     budget at 2 waves/SIMD; vs round 6 this moves 48 floats off the
//     AGPR-move tax, vs round 5 it deletes 20/32 DS ops per thread.
//  3. reduction tail: single-pass u64 DPP max (rocPRIM wave64 ladder:
//     row_shr 1/2/4/8 + row_bcast 15/31) on key = bits(dist)<<32 | ~idx
//     (u64-max == (max dist, min idx) == reference first-argmax, proven
//     since round 0); cross-wave combine = 3-level u64 DPP over the 8 LDS
//     keys + readlane(7) instead of 6 ds_bpermute.
// Quad-latch argmax + descending-priority element resolve verbatim from
// round 6 (fmax returns operands bitwise -> equality resolve exact).

// d_out layout (float32, concatenated):
//   [0, B*S*3)                      new_xyz  (B,S,3)
//   [B*S*3, B*S*3+B*C*S)            new_fea  (B,C,S)
//   [B*S*3+B*C*S, +B*S)             indices  (B,S) as float

// u64 max across lanes via DPP (old kept where source lane invalid):
#define U64_DPP_MAX(k, ctrl)                                                \
  {                                                                         \
    const u32 lo_ = (u32)(k), hi_ = (u32)((k) >> 32);                       \
    const u32 nlo_ = (u32)__builtin_amdgcn_update_dpp(                      \
        (int)lo_, (int)lo_, (ctrl), 0xf, 0xf, false);                       \
    const u32 nhi_ = (u32)__builtin_amdgcn_update_dpp(                      \
        (int)hi_, (int)hi_, (ctrl), 0xf, 0xf, false);                       \
    const u64 ok_ = ((u64)nhi_ << 32) | nlo_;                               \
    if (ok_ > (k)) (k) = ok_;                                               \
  }

__global__ __launch_bounds__(T_)
__attribute__((amdgpu_waves_per_eu(2, 2)))   // 8 waves = 2/SIMD -> 256-reg budget
void fps_kernel(
    const float* __restrict__ xyz,   // (B, N, 3)
    float* __restrict__ out)
{
#pragma clang fp contract(off)
  const int b    = blockIdx.x;       // one block per batch
  const int t    = threadIdx.x;
  const int lane = t & 63;
  const int w    = t >> 6;
  const float* xb = xyz + (size_t)b * N_ * 3;

  float* out_xyz = out;
  float* out_idx = out + (size_t)B_*S_*3 + (size_t)B_*C_*S_;

  __shared__ f4v CS[LQP][3][T_];     // 96 KB read-only coords, quads 12..15
  __shared__ u64 red[2][W_];         // per-wave winner keys, parity dbuf

  // Reg coords: pair k covers ordinals j = 2k, 2k+1 (point g = j*T_ + t;
  // ascending j -> first-max scan == smallest global index).
  f2v XR[2*RQP], YR[2*RQP], ZR[2*RQP];
  f2v Dr[2*NQ];                      // running min-dists, all 64 in regs
  #pragma unroll
  for (int k = 0; k < 2*RQP; ++k) {
    const int g0 = (2*k)   * T_ + t;
    const int g1 = (2*k+1) * T_ + t;
    XR[k] = (f2v){xb[g0*3+0], xb[g1*3+0]};
    YR[k] = (f2v){xb[g0*3+1], xb[g1*3+1]};
    ZR[k] = (f2v){xb[g0*3+2], xb[g1*3+2]};
  }
  #pragma unroll
  for (int k = 0; k < 2*RQP; ++k) {
    asm volatile("" : "+v"(XR[k]), "+v"(YR[k]), "+v"(ZR[k]));  // no remat
  }
  // LDS coords for quads RQP..NQ-1 (private column t, b128 rows).
  #pragma unroll
  for (int q = 0; q < LQP; ++q) {
    f4v vx, vy, vz;
    #pragma unroll
    for (int e = 0; e < 4; ++e) {
      const int g = ((RQP + q) * 4 + e) * T_ + t;
      vx[e] = xb[g*3+0];
      vy[e] = xb[g*3+1];
      vz[e] = xb[g*3+2];
    }
    CS[q][0][t] = vx; CS[q][1][t] = vy; CS[q][2][t] = vz;
  }
  #pragma unroll
  for (int k = 0; k < 2*NQ; ++k) Dr[k] = (f2v){1e10f, 1e10f};
  __syncthreads();

  int cur = 0;
  for (int s = 0; s < S_; ++s) {
    const int cu = __builtin_amdgcn_readfirstlane(cur);   // uniform -> scalar loads
    const float cx = xb[cu*3+0];
    const float cy = xb[cu*3+1];
    const float cz = xb[cu*3+2];
    if (t == 0) {
      out_idx[(size_t)b*S_ + s] = (float)cu;
      float* o = out_xyz + ((size_t)b*S_ + s)*3;
      o[0] = cx; o[1] = cy; o[2] = cz;
    }
    const f2v c2x = (f2v){cx, cx};
    const f2v c2y = (f2v){cy, cy};
    const f2v c2z = (f2v){cz, cz};

    // Exact IEEE ((dx*dx + dy*dy) + dz*dz), no contraction, packed pairs.
    // Quad latch: (max, first quad) + the quad's nd values for resolve.
    float bv = -1.0f;
    int   bq = 0;
    f2v nw01 = (f2v){0.f, 0.f}, nw23 = (f2v){0.f, 0.f};

    #define UQ(qc, xa, ya, za, xb2, yb2, zb2)                              \
      {                                                                    \
        const f2v dx0 = (xa) - c2x;                                        \
        const f2v dy0 = (ya) - c2y;                                        \
        const f2v dz0 = (za) - c2z;                                        \
        const f2v d0  = (dx0*dx0 + dy0*dy0) + dz0*dz0;                     \
        const f2v dx1 = (xb2) - c2x;                                       \
        const f2v dy1 = (yb2) - c2y;                                       \
        const f2v dz1 = (zb2) - c2z;                                       \
        const f2v d1  = (dx1*dx1 + dy1*dy1) + dz1*dz1;                     \
        const f2v nd0 = __builtin_elementwise_min(Dr[2*(qc)],   d0);       \
        const f2v nd1 = __builtin_elementwise_min(Dr[2*(qc)+1], d1);       \
        Dr[2*(qc)]   = nd0;                                                \
        Dr[2*(qc)+1] = nd1;                                                \
        const f2v qm2 = __builtin_elementwise_max(nd0, nd1);               \
        const float qm = fmaxf(qm2.x, qm2.y);                              \
        if (qm > bv) { bv = qm; bq = (qc); nw01 = nd0; nw23 = nd1; }       \
      }

    // Prefetch first LDS quad; LDS quads are consumed last (j order!).
    f4v px = CS[0][0][t], py = CS[0][1][t], pz = CS[0][2][t];

    #pragma unroll
    for (int q = 0; q < RQP; ++q) {
      UQ(q, XR[2*q], YR[2*q], ZR[2*q], XR[2*q+1], YR[2*q+1], ZR[2*q+1]);
    }
    #pragma unroll
    for (int q = 0; q < LQP; ++q) {
      const f4v qx = px, qy = py, qz = pz;
      if (q + 1 < LQP) {             // 1-ahead rolling prefetch
        px = CS[q+1][0][t]; py = CS[q+1][1][t]; pz = CS[q+1][2][t];
      }
      const f2v ax = (f2v){qx[0], qx[1]}, ay = (f2v){qy[0], qy[1]},
                az = (f2v){qz[0], qz[1]};
      const f2v bx = (f2v){qx[2], qx[3]}, by = (f2v){qy[2], qy[3]},
                bz = (f2v){qz[2], qz[3]};
      UQ(RQP + q, ax, ay, az, bx, by, bz);
    }
    #undef UQ

    // Element within winning quad from latched nd regs (fmax returns its
    // operands bitwise -> equality holds). Descending priority == first.
    int e = 3;
    if (nw23.x == bv) e = 2;
    if (nw01.y == bv) e = 1;
    if (nw01.x == bv) e = 0;
    const int bj = (bq << 2) + e;    // per-thread point ordinal 0..63
    const int bg = (bj << 9) + t;    // global point index (T_ == 512)

    // Single-pass u64 DPP wave max on key = (bits(bv)<<32) | ~bg:
    // u64-max == (max dist, min idx). Lane 63 ends with the wave key.
    u64 key = ((u64)__float_as_uint(bv) << 32) | (u32)(~bg);
    U64_DPP_MAX(key, 0x111);         // row_shr:1
    U64_DPP_MAX(key, 0x112);         // row_shr:2
    U64_DPP_MAX(key, 0x114);         // row_shr:4
    U64_DPP_MAX(key, 0x118);         // row_shr:8
    U64_DPP_MAX(key, 0x142);         // row_bcast:15
    U64_DPP_MAX(key, 0x143);         // row_bcast:31
    if (lane == 63) red[s & 1][w] = key;
    __syncthreads();

    // Cross-wave: read 8 keys, 3-level u64 DPP reduce within 8-lane groups
    // (lane 7 of each group holds the block max), broadcast via readlane.
    u64 k = red[s & 1][lane & (W_ - 1)];
    U64_DPP_MAX(k, 0x111);           // row_shr:1
    U64_DPP_MAX(k, 0x112);           // row_shr:2
    U64_DPP_MAX(k, 0x114);           // row_shr:4
    cur = (int)~(u32)__builtin_amdgcn_readlane((int)(u32)k, 7);
  }
}

__global__ void gather_fea_kernel(
    const float* __restrict__ feat,   // (B, C, N)
    const float* __restrict__ idxf,   // (B, S) float indices (in d_out)
    float* __restrict__ out_fea)      // (B, C, S)
{
  const int t = blockIdx.x * blockDim.x + threadIdx.x;
  if (t >= B_ * C_ * S_) return;
  const int s  = t & (S_ - 1);
  const int bc = t >> 10;           // S_ == 1024
  const int c  = bc % C_;
  const int b  = bc / C_;
  const int idx = (int)idxf[(size_t)b * S_ + s];
  out_fea[t] = feat[((size_t)b * C_ + c) * (size_t)N_ + idx];
}

extern "C" void kernel_launch(void* const* d_in, const int* in_sizes, int n_in,
                              void* d_out, int out_size, void* d_ws, size_t ws_size,
                              hipStream_t stream) {
  const float* xyz  = (const float*)d_in[0];   // (B,N,3)
  const float* feat = (const float*)d_in[1];   // (B,C,N)
  float* out = (float*)d_out;

  float* out_fea = out + (size_t)B_ * S_ * 3;
  float* out_idx = out + (size_t)B_ * S_ * 3 + (size_t)B_ * C_ * S_;
  (void)d_ws; (void)ws_size; (void)in_sizes; (void)n_in; (void)out_size;

  fps_kernel<<<B_, T_, 0, stream>>>(xyz, out);

  const int total = B_ * C_ * S_;
  gather_fea_kernel<<<(total + 255) / 256, 256, 0, stream>>>(feat, out_idx, out_fea);
}

// Round 8
// 2140.274 us; speedup vs baseline: 1.3497x; 1.2128x over previous
//
#include <hip/hip_runtime.h>

#define B_ 8
#define N_ 32768
#define S_ 1024
#define C_ 96
#define P_ 2               // blocks per batch (round-0-proven agent-scope exchange)
#define T_ 512             // 8 waves per block
#define W_ (T_ / 64)
#define HALF (N_ / P_)     // 16384 points per block
#define PPT (HALF / T_)    // 32 points per thread
#define NQ (PPT / 4)       // 8 quads per thread
#define PRS (PPT / 2)      // 16 coord pairs per thread

typedef float f2v __attribute__((ext_vector_type(2)));
typedef unsigned long long u64;
typedef unsigned int u32;

// Round 8: P=2 batch split. Round 7 hit 79% of the single-CU VALU issue
// ceiling -- the wall is one CU issuing all 98K distance instrs/step plus
// an AGPR-move tax (208 floats vs the 128/128 VGPR/AGPR split). Round 0's
// corrected numbers (FETCH in KB -> polls are L3-served, ~500-600 cy RT)
// show sync cost was dominated by 32 PARTICIPANTS (straggler visibility x
// poll iters x butterflies), not by transport latency. With P=2:
//   - each block's half-batch state (96 coord + 32 D floats) fits entirely
//     in arch VGPRs: no AGPR split, no LDS coords, zero DS ops in the loop.
//   - sync = store own key + poll PARTNER's slot only (own key stays in
//     registers -> own-store visibility off the critical path) + 1 compare.
//   - transport = verbatim round-0 protocol (passed repeatedly): relaxed
//     agent-scope atomics, fresh slot row per (batch, step) -> no ABA,
//     key-is-payload (never 0), both blocks publish before polling every
//     step -> deadlock-free; fast block may run at most ahead until it
//     polls a row the laggard hasn't reached, then waits. All slot stores
//     are agent-scope -- no mixed-scope cache lines (round-2 bug class).
// Distance expression ((dx*dx+dy*dy)+dz*dz, contract off), packed f2v
// math, quad-latch argmax, element resolve, u64 DPP wave/block reduce:
// all verbatim from round 7 (proven absmax 0). Key = bits(dist)<<32 | ~idx
// makes u64-max == (max dist, min idx) across the whole batch regardless
// of which block owns the point.

// d_out layout (float32, concatenated):
//   [0, B*S*3)                      new_xyz  (B,S,3)
//   [B*S*3, B*S*3+B*C*S)            new_fea  (B,C,S)  <- doubles as slot scratch
//   [B*S*3+B*C*S, +B*S)             indices  (B,S) as float

// u64 max across lanes via DPP (old kept where source lane invalid):
#define U64_DPP_MAX(k, ctrl)                                                \
  {                                                                         \
    const u32 lo_ = (u32)(k), hi_ = (u32)((k) >> 32);                       \
    const u32 nlo_ = (u32)__builtin_amdgcn_update_dpp(                      \
        (int)lo_, (int)lo_, (ctrl), 0xf, 0xf, false);                       \
    const u32 nhi_ = (u32)__builtin_amdgcn_update_dpp(                      \
        (int)hi_, (int)hi_, (ctrl), 0xf, 0xf, false);                       \
    const u64 ok_ = ((u64)nhi_ << 32) | nlo_;                               \
    if (ok_ > (k)) (k) = ok_;                                               \
  }

__global__ __launch_bounds__(T_)
__attribute__((amdgpu_waves_per_eu(2, 2)))   // 8 waves = 2/SIMD -> 256-reg budget
void fps_kernel(
    const float* __restrict__ xyz,   // (B, N, 3)
    float* __restrict__ out,
    u64* __restrict__ parts)         // (B_*S_, P_) key slots, pre-zeroed
{
#pragma clang fp contract(off)
  const int blk  = blockIdx.x;
  const int b    = blk & 7;          // batch (blk and blk+8 pair up per batch)
  const int m    = blk >> 3;         // half 0..1
  const int t    = threadIdx.x;
  const int lane = t & 63;
  const int w    = t >> 6;
  const float* xb = xyz + (size_t)b * N_ * 3;
  const int base = m * HALF;

  float* out_xyz = out;
  float* out_idx = out + (size_t)B_*S_*3 + (size_t)B_*C_*S_;

  __shared__ u64 red[2][W_];         // per-wave winner keys, parity dbuf

  // Half-batch coords + min-dists fully in arch VGPRs (96 + 32 floats).
  // Pair k covers ordinals j = 2k, 2k+1; point g = base + j*T_ + t
  // (ascending j -> per-thread first-max scan == smallest global index).
  f2v XR[PRS], YR[PRS], ZR[PRS], Dr[PRS];
  #pragma unroll
  for (int k = 0; k < PRS; ++k) {
    const int g0 = base + (2*k)   * T_ + t;
    const int g1 = base + (2*k+1) * T_ + t;
    XR[k] = (f2v){xb[g0*3+0], xb[g1*3+0]};
    YR[k] = (f2v){xb[g0*3+1], xb[g1*3+1]};
    ZR[k] = (f2v){xb[g0*3+2], xb[g1*3+2]};
    Dr[k] = (f2v){1e10f, 1e10f};
  }
  #pragma unroll
  for (int k = 0; k < PRS; ++k) {
    asm volatile("" : "+v"(XR[k]), "+v"(YR[k]), "+v"(ZR[k]));  // no remat
  }

  int cur = 0;
  for (int s = 0; s < S_; ++s) {
    const int cu = __builtin_amdgcn_readfirstlane(cur);   // uniform -> scalar loads
    const float cx = xb[cu*3+0];
    const float cy = xb[cu*3+1];
    const float cz = xb[cu*3+2];
    if (m == 0 && t == 0) {
      out_idx[(size_t)b*S_ + s] = (float)cu;
      float* o = out_xyz + ((size_t)b*S_ + s)*3;
      o[0] = cx; o[1] = cy; o[2] = cz;
    }
    const f2v c2x = (f2v){cx, cx};
    const f2v c2y = (f2v){cy, cy};
    const f2v c2z = (f2v){cz, cz};

    // Exact IEEE ((dx*dx + dy*dy) + dz*dz), no contraction, packed pairs.
    // Quad latch: (max, first quad) + the quad's nd values for resolve.
    float bv = -1.0f;
    int   bq = 0;
    f2v nw01 = (f2v){0.f, 0.f}, nw23 = (f2v){0.f, 0.f};

    #define UQ(qc)                                                         \
      {                                                                    \
        const f2v dx0 = XR[2*(qc)]   - c2x;                                \
        const f2v dy0 = YR[2*(qc)]   - c2y;                                \
        const f2v dz0 = ZR[2*(qc)]   - c2z;                                \
        const f2v d0  = (dx0*dx0 + dy0*dy0) + dz0*dz0;                     \
        const f2v dx1 = XR[2*(qc)+1] - c2x;                                \
        const f2v dy1 = YR[2*(qc)+1] - c2y;                                \
        const f2v dz1 = ZR[2*(qc)+1] - c2z;                                \
        const f2v d1  = (dx1*dx1 + dy1*dy1) + dz1*dz1;                     \
        const f2v nd0 = __builtin_elementwise_min(Dr[2*(qc)],   d0);       \
        const f2v nd1 = __builtin_elementwise_min(Dr[2*(qc)+1], d1);       \
        Dr[2*(qc)]   = nd0;                                                \
        Dr[2*(qc)+1] = nd1;                                                \
        const f2v qm2 = __builtin_elementwise_max(nd0, nd1);               \
        const float qm = fmaxf(qm2.x, qm2.y);                              \
        if (qm > bv) { bv = qm; bq = (qc); nw01 = nd0; nw23 = nd1; }       \
      }
    #pragma unroll
    for (int q = 0; q < NQ; ++q) { UQ(q); }
    #undef UQ

    // Element within winning quad from latched nd regs (fmax returns its
    // operands bitwise -> equality holds). Descending priority == first.
    int e = 3;
    if (nw23.x == bv) e = 2;
    if (nw01.y == bv) e = 1;
    if (nw01.x == bv) e = 0;
    const int bj = (bq << 2) + e;          // per-thread ordinal 0..31
    const int bg = base + (bj << 9) + t;   // global point index (T_ == 512)

    // Single-pass u64 DPP wave max on key = (bits(bv)<<32) | ~bg:
    // u64-max == (max dist, min idx). Lane 63 ends with the wave key.
    u64 key = ((u64)__float_as_uint(bv) << 32) | (u32)(~bg);
    U64_DPP_MAX(key, 0x111);         // row_shr:1
    U64_DPP_MAX(key, 0x112);         // row_shr:2
    U64_DPP_MAX(key, 0x114);         // row_shr:4
    U64_DPP_MAX(key, 0x118);         // row_shr:8
    U64_DPP_MAX(key, 0x142);         // row_bcast:15
    U64_DPP_MAX(key, 0x143);         // row_bcast:31
    if (lane == 63) red[s & 1][w] = key;
    __syncthreads();

    // Cross-wave: 8 keys, 3-level u64 DPP within 8-lane groups, lane 7
    // holds the block max; broadcast via readlane (uniform in all threads).
    u64 k = red[s & 1][lane & (W_ - 1)];
    U64_DPP_MAX(k, 0x111);
    U64_DPP_MAX(k, 0x112);
    U64_DPP_MAX(k, 0x114);
    const u32 klo = (u32)__builtin_amdgcn_readlane((int)(u32)k, 7);
    const u32 khi = (u32)__builtin_amdgcn_readlane((int)(k >> 32), 7);
    const u64 kblk = ((u64)khi << 32) | klo;

    // Inter-block exchange, round-0-proven transport: publish own key
    // (agent scope, relaxed), poll PARTNER's slot only (own key is in
    // registers), combine. Row is fresh per step -> no ABA; key != 0.
    u64* row = parts + ((size_t)(b * S_ + s) << 1);
    if (t == 0) {
      __hip_atomic_store(&row[m], kblk, __ATOMIC_RELAXED,
                         __HIP_MEMORY_SCOPE_AGENT);
    }
    u64 ko;
    do {
      ko = __hip_atomic_load(&row[1 - m], __ATOMIC_RELAXED,
                             __HIP_MEMORY_SCOPE_AGENT);
    } while (__ballot(ko != 0) != ~0ull);
    const u64 kw = (ko > kblk) ? ko : kblk;
    cur = (int)(u32)(~(u32)kw);            // decode winner index
  }
}

__global__ void gather_fea_kernel(
    const float* __restrict__ feat,   // (B, C, N)
    const float* __restrict__ idxf,   // (B, S) float indices (in d_out)
    float* __restrict__ out_fea)      // (B, C, S)
{
  const int t = blockIdx.x * blockDim.x + threadIdx.x;
  if (t >= B_ * C_ * S_) return;
  const int s  = t & (S_ - 1);
  const int bc = t >> 10;           // S_ == 1024
  const int c  = bc % C_;
  const int b  = bc / C_;
  const int idx = (int)idxf[(size_t)b * S_ + s];
  out_fea[t] = feat[((size_t)b * C_ + c) * (size_t)N_ + idx];
}

extern "C" void kernel_launch(void* const* d_in, const int* in_sizes, int n_in,
                              void* d_out, int out_size, void* d_ws, size_t ws_size,
                              hipStream_t stream) {
  const float* xyz  = (const float*)d_in[0];   // (B,N,3)
  const float* feat = (const float*)d_in[1];   // (B,C,N)
  float* out = (float*)d_out;

  float* out_fea = out + (size_t)B_ * S_ * 3;
  float* out_idx = out + (size_t)B_ * S_ * 3 + (size_t)B_ * C_ * S_;
  (void)d_ws; (void)ws_size; (void)in_sizes; (void)n_in; (void)out_size;

  // Slot scratch lives in the out_fea region (3 MB >= 128 KB needed); it is
  // fully overwritten by gather_fea_kernel afterwards. Zero it (poisoned 0xAA).
  u64* parts = (u64*)out_fea;
  hipMemsetAsync(parts, 0, (size_t)B_ * S_ * P_ * sizeof(u64), stream);

  fps_kernel<<<B_ * P_, T_, 0, stream>>>(xyz, out, parts);

  const int total = B_ * C_ * S_;
  gather_fea_kernel<<<(total + 255) / 256, 256, 0, stream>>>(feat, out_idx, out_fea);
}

// Round 9
// 2109.055 us; speedup vs baseline: 1.3697x; 1.0148x over previous
//
#include <hip/hip_runtime.h>

#define B_ 8
#define N_ 32768
#define S_ 1024
#define C_ 96
#define P_ 2               // blocks per batch
#define T_ 512             // 8 waves per block
#define W_ (T_ / 64)
#define HALF (N_ / P_)     // 16384 points per block
#define PPT (HALF / T_)    // 32 points per thread
#define NQ (PPT / 4)       // 8 quads per thread
#define PRS (PPT / 2)      // 16 coord pairs per thread

typedef float f2v __attribute__((ext_vector_type(2)));
typedef unsigned long long u64;
typedef unsigned int u32;

// Round 9: round 8 (passed, 2013 us fps) still pays ~2200 cy/step for the
// agent-scope (sc1) exchange -- sc1 ops are serviced at the device coherence
// point (~600-900 cy each way). Batch b's two blocks are blk=b and blk=b+8:
// under round-robin dispatch BOTH land on XCD b%8 and share one L2, where an
// exchange costs ~200-250 cy. This round adds that fast path with every prior
// failure mode excluded by construction:
//   r1 bug (RMW poll storm serializing at TCC): poll is a plain sc0 LOAD
//     (L1-bypass, L2-served, broadcast to the wave) -- no RMWs anywhere.
//   r2 bug (plain-stored dirty lines clobbering agent keys on eviction):
//     TWO DISJOINT BUFFERS -- partsL (local transport, plain stores) and
//     partsA (agent transport, sc1 stores) never share a cache line.
//   hang safety: lane 0 publishes to the AGENT buffer every step
//     unconditionally, so the round-8-proven agent path is always live.
//     Local poll is bounded (256 tries at s==0 for dispatch stagger, 12
//     after); on timeout the wave demotes PERMANENTLY to agent polling.
//     Worst case = round-8 behavior + one-time ~70 us spin. No unbounded
//     wait ever depends on placement (G16). Dirty local lines are written
//     back at kernel-end release before gather_fea overwrites the region.
// Everything else (packed f2v distance chain, contract off, quad-latch
// argmax, element resolve, u64 DPP wave/block reduce, key encoding) is
// byte-identical to round 8 -> identical winners, absmax 0.

// d_out layout (float32, concatenated):
//   [0, B*S*3)                      new_xyz  (B,S,3)
//   [B*S*3, B*S*3+B*C*S)            new_fea  (B,C,S)  <- doubles as slot scratch
//   [B*S*3+B*C*S, +B*S)             indices  (B,S) as float

// u64 max across lanes via DPP (old kept where source lane invalid):
#define U64_DPP_MAX(k, ctrl)                                                \
  {                                                                         \
    const u32 lo_ = (u32)(k), hi_ = (u32)((k) >> 32);                       \
    const u32 nlo_ = (u32)__builtin_amdgcn_update_dpp(                      \
        (int)lo_, (int)lo_, (ctrl), 0xf, 0xf, false);                       \
    const u32 nhi_ = (u32)__builtin_amdgcn_update_dpp(                      \
        (int)hi_, (int)hi_, (ctrl), 0xf, 0xf, false);                       \
    const u64 ok_ = ((u64)nhi_ << 32) | nlo_;                               \
    if (ok_ > (k)) (k) = ok_;                                               \
  }

// L1-bypass load served by the XCD-local L2 (sc0 == GLC on gfx940+).
__device__ __forceinline__ u64 ld_sc0(const u64* p) {
  u64 v;
  asm volatile("global_load_dwordx2 %0, %1, off sc0\n\t"
               "s_waitcnt vmcnt(0)"
               : "=v"(v) : "v"(p) : "memory");
  return v;
}

__global__ __launch_bounds__(T_)
__attribute__((amdgpu_waves_per_eu(2, 2)))   // 8 waves = 2/SIMD -> 256-reg budget
void fps_kernel(
    const float* __restrict__ xyz,   // (B, N, 3)
    float* __restrict__ out,
    u64* __restrict__ partsA,        // (B_*S_, P_) agent-scope slots, pre-zeroed
    u64* __restrict__ partsL)        // (B_*S_, P_) local-L2 slots, pre-zeroed
{
#pragma clang fp contract(off)
  const int blk  = blockIdx.x;
  const int b    = blk & 7;          // batch (blk and blk+8 pair -> same XCD heur.)
  const int m    = blk >> 3;         // half 0..1
  const int t    = threadIdx.x;
  const int lane = t & 63;
  const int w    = t >> 6;
  const float* xb = xyz + (size_t)b * N_ * 3;
  const int base = m * HALF;

  float* out_xyz = out;
  float* out_idx = out + (size_t)B_*S_*3 + (size_t)B_*C_*S_;

  __shared__ u64 red[2][W_];         // per-wave winner keys, parity dbuf

  // Half-batch coords + min-dists fully in arch VGPRs (96 + 32 floats).
  // Pair k covers ordinals j = 2k, 2k+1; point g = base + j*T_ + t
  // (ascending j -> per-thread first-max scan == smallest global index).
  f2v XR[PRS], YR[PRS], ZR[PRS], Dr[PRS];
  #pragma unroll
  for (int k = 0; k < PRS; ++k) {
    const int g0 = base + (2*k)   * T_ + t;
    const int g1 = base + (2*k+1) * T_ + t;
    XR[k] = (f2v){xb[g0*3+0], xb[g1*3+0]};
    YR[k] = (f2v){xb[g0*3+1], xb[g1*3+1]};
    ZR[k] = (f2v){xb[g0*3+2], xb[g1*3+2]};
    Dr[k] = (f2v){1e10f, 1e10f};
  }
  #pragma unroll
  for (int k = 0; k < PRS; ++k) {
    asm volatile("" : "+v"(XR[k]), "+v"(YR[k]), "+v"(ZR[k]));  // no remat
  }

  bool fastmode = true;              // per-wave sticky; demote on local timeout
  int cur = 0;
  for (int s = 0; s < S_; ++s) {
    const int cu = __builtin_amdgcn_readfirstlane(cur);   // uniform -> scalar loads
    const float cx = xb[cu*3+0];
    const float cy = xb[cu*3+1];
    const float cz = xb[cu*3+2];
    if (m == 0 && t == 0) {
      out_idx[(size_t)b*S_ + s] = (float)cu;
      float* o = out_xyz + ((size_t)b*S_ + s)*3;
      o[0] = cx; o[1] = cy; o[2] = cz;
    }
    const f2v c2x = (f2v){cx, cx};
    const f2v c2y = (f2v){cy, cy};
    const f2v c2z = (f2v){cz, cz};

    // Exact IEEE ((dx*dx + dy*dy) + dz*dz), no contraction, packed pairs.
    // Quad latch: (max, first quad) + the quad's nd values for resolve.
    float bv = -1.0f;
    int   bq = 0;
    f2v nw01 = (f2v){0.f, 0.f}, nw23 = (f2v){0.f, 0.f};

    #define UQ(qc)                                                         \
      {                                                                    \
        const f2v dx0 = XR[2*(qc)]   - c2x;                                \
        const f2v dy0 = YR[2*(qc)]   - c2y;                                \
        const f2v dz0 = ZR[2*(qc)]   - c2z;                                \
        const f2v d0  = (dx0*dx0 + dy0*dy0) + dz0*dz0;                     \
        const f2v dx1 = XR[2*(qc)+1] - c2x;                                \
        const f2v dy1 = YR[2*(qc)+1] - c2y;                                \
        const f2v dz1 = ZR[2*(qc)+1] - c2z;                                \
        const f2v d1  = (dx1*dx1 + dy1*dy1) + dz1*dz1;                     \
        const f2v nd0 = __builtin_elementwise_min(Dr[2*(qc)],   d0);       \
        const f2v nd1 = __builtin_elementwise_min(Dr[2*(qc)+1], d1);       \
        Dr[2*(qc)]   = nd0;                                                \
        Dr[2*(qc)+1] = nd1;                                                \
        const f2v qm2 = __builtin_elementwise_max(nd0, nd1);               \
        const float qm = fmaxf(qm2.x, qm2.y);                              \
        if (qm > bv) { bv = qm; bq = (qc); nw01 = nd0; nw23 = nd1; }       \
      }
    #pragma unroll
    for (int q = 0; q < NQ; ++q) { UQ(q); }
    #undef UQ

    // Element within winning quad from latched nd regs (fmax returns its
    // operands bitwise -> equality holds). Descending priority == first.
    int e = 3;
    if (nw23.x == bv) e = 2;
    if (nw01.y == bv) e = 1;
    if (nw01.x == bv) e = 0;
    const int bj = (bq << 2) + e;          // per-thread ordinal 0..31
    const int bg = base + (bj << 9) + t;   // global point index (T_ == 512)

    // Single-pass u64 DPP wave max on key = (bits(bv)<<32) | ~bg:
    // u64-max == (max dist, min idx). Lane 63 ends with the wave key.
    u64 key = ((u64)__float_as_uint(bv) << 32) | (u32)(~bg);
    U64_DPP_MAX(key, 0x111);         // row_shr:1
    U64_DPP_MAX(key, 0x112);         // row_shr:2
    U64_DPP_MAX(key, 0x114);         // row_shr:4
    U64_DPP_MAX(key, 0x118);         // row_shr:8
    U64_DPP_MAX(key, 0x142);         // row_bcast:15
    U64_DPP_MAX(key, 0x143);         // row_bcast:31
    if (lane == 63) red[s & 1][w] = key;
    __syncthreads();

    // Cross-wave: 8 keys, 3-level u64 DPP within 8-lane groups, lane 7
    // holds the block max; broadcast via readlane (uniform in all threads).
    u64 k = red[s & 1][lane & (W_ - 1)];
    U64_DPP_MAX(k, 0x111);
    U64_DPP_MAX(k, 0x112);
    U64_DPP_MAX(k, 0x114);
    const u32 klo = (u32)__builtin_amdgcn_readlane((int)(u32)k, 7);
    const u32 khi = (u32)__builtin_amdgcn_readlane((int)(k >> 32), 7);
    const u64 kblk = ((u64)khi << 32) | klo;

    // Inter-block exchange: publish to BOTH buffers (local = plain write-
    // through store to the shared L2 if co-located; agent = sc1, always
    // live for the fallback). Poll partner's LOCAL slot bounded; demote
    // permanently to the round-8-proven agent poll on timeout. Rows are
    // fresh per (batch, step) -> no ABA; keys never 0.
    u64* rowA = partsA + ((size_t)(b * S_ + s) << 1);
    u64* rowL = partsL + ((size_t)(b * S_ + s) << 1);
    if (t == 0) {
      __hip_atomic_store(&rowL[m], kblk, __ATOMIC_RELAXED,
                         __HIP_MEMORY_SCOPE_WORKGROUP);
      __hip_atomic_store(&rowA[m], kblk, __ATOMIC_RELAXED,
                         __HIP_MEMORY_SCOPE_AGENT);
    }
    u64 ko = 0;
    if (fastmode) {
      const int tries = (s == 0) ? 256 : 12;   // dispatch-stagger warmup
      for (int i = 0; i < tries; ++i) {
        ko = ld_sc0(rowL + (1 - m));           // same addr all lanes: 1 line
        if (__ballot(ko != 0) == ~0ull) break;
      }
      if (__ballot(ko != 0) != ~0ull) { fastmode = false; ko = 0; }
    }
    if (ko == 0) {
      // Agent-scope fallback: exactly the round-8-proven transport.
      do {
        ko = __hip_atomic_load(&rowA[1 - m], __ATOMIC_RELAXED,
                               __HIP_MEMORY_SCOPE_AGENT);
      } while (__ballot(ko != 0) != ~0ull);
    }
    const u64 kw = (ko > kblk) ? ko : kblk;
    cur = (int)(u32)(~(u32)kw);            // decode winner index
  }
}

__global__ void gather_fea_kernel(
    const float* __restrict__ feat,   // (B, C, N)
    const float* __restrict__ idxf,   // (B, S) float indices (in d_out)
    float* __restrict__ out_fea)      // (B, C, S)
{
  const int t = blockIdx.x * blockDim.x + threadIdx.x;
  if (t >= B_ * C_ * S_) return;
  const int s  = t & (S_ - 1);
  const int bc = t >> 10;           // S_ == 1024
  const int c  = bc % C_;
  const int b  = bc / C_;
  const int idx = (int)idxf[(size_t)b * S_ + s];
  out_fea[t] = feat[((size_t)b * C_ + c) * (size_t)N_ + idx];
}

extern "C" void kernel_launch(void* const* d_in, const int* in_sizes, int n_in,
                              void* d_out, int out_size, void* d_ws, size_t ws_size,
                              hipStream_t stream) {
  const float* xyz  = (const float*)d_in[0];   // (B,N,3)
  const float* feat = (const float*)d_in[1];   // (B,C,N)
  float* out = (float*)d_out;

  float* out_fea = out + (size_t)B_ * S_ * 3;
  float* out_idx = out + (size_t)B_ * S_ * 3 + (size_t)B_ * C_ * S_;
  (void)d_ws; (void)ws_size; (void)in_sizes; (void)n_in; (void)out_size;

  // Slot scratch lives in the out_fea region (3 MB >= 256 KB needed); it is
  // fully overwritten by gather_fea_kernel afterwards. Two DISJOINT buffers:
  // agent-scope slots then local-L2 slots (never share a cache line).
  u64* partsA = (u64*)out_fea;
  u64* partsL = partsA + (size_t)B_ * S_ * P_;
  hipMemsetAsync(partsA, 0, (size_t)2 * B_ * S_ * P_ * sizeof(u64), stream);

  fps_kernel<<<B_ * P_, T_, 0, stream>>>(xyz, out, partsA, partsL);

  const int total = B_ * C_ * S_;
  gather_fea_kernel<<<(total + 255) / 256, 256, 0, stream>>>(feat, out_idx, out_fea);
}

// Round 10
// 1904.263 us; speedup vs baseline: 1.5170x; 1.1075x over previous
//
#include <hip/hip_runtime.h>

#define B_ 8
#define N_ 32768
#define S_ 1024
#define C_ 96
#define P_ 4               // blocks per batch (measured-XCD co-located quads)
#define T_ 512             // 8 waves per block
#define W_ (T_ / 64)
#define QTR (N_ / P_)      // 8192 points per block
#define PPT (QTR / T_)     // 16 points per thread
#define NQ (PPT / 4)       // 4 quads per thread
#define PRS (PPT / 2)      // 8 coord pairs per thread
#define NBLK (B_ * P_)     // 32 blocks

typedef float f2v __attribute__((ext_vector_type(2)));
typedef unsigned long long u64;
typedef unsigned int u32;

// Round 10. Round 9's flat result + FETCH barely moving showed the blk/blk+8
// co-location HEURISTIC failed (placement is undefined, G16) and the polling
// wave's wave-level vmcnt(0) drained its own sc1 store ack into every poll.
// This round:
//  1. P=4: halves per-SIMD VALU issue (measured 57% of the step at P=2);
//     8192 pts/block keeps all state in arch VGPRs (48+16 floats).
//  2. MEASURED pairing: each block agent-publishes its HW_REG_XCC_ID once;
//     every block computes the same deterministic rank over (xcd, blkid) ->
//     (batch, quarter). A batch's 4 blocks share an XCD by construction
//     whenever placement permits; fast_ok is ground truth, not a guess.
//     Non-co-located batches statically use the round-8-proven agent path.
//  3. store/poll wave split: wave 1 publishes BOTH transports every step
//     (fallback always live); wave 0 polls (no stores -> vmcnt is pure load
//     RT); winner broadcast via LDS + 2nd barrier.
// Graveyard audit: no atomic RMWs (r1 bug). partsL rows padded to 128 B --
// one batch per line, local plain stores only, and only read when fast_ok
// (r2 bug: no mixed-scope or cross-XCD dirty-line sharing; memset zeros are
// flushed to the coherence point before the kernel starts, so local write-
// allocate pulls clean zeros). Discovery and main loop publish-before-poll
// with all 32 blocks resident (r0/r8-proven). Local poll bounded + sticky
// demotion -> hang-impossible; worst case = agent path at half compute.
// Compute, key encoding, DPP ladders, tie-breaks: verbatim from r8/r9.

// d_out layout (float32, concatenated):
//   [0, B*S*3)                      new_xyz  (B,S,3)
//   [B*S*3, B*S*3+B*C*S)            new_fea  (B,C,S)  <- doubles as slot scratch
//   [B*S*3+B*C*S, +B*S)             indices  (B,S) as float

// u64 max across lanes via DPP (old kept where source lane invalid):
#define U64_DPP_MAX(k, ctrl)                                                \
  {                                                                         \
    const u32 lo_ = (u32)(k), hi_ = (u32)((k) >> 32);                       \
    const u32 nlo_ = (u32)__builtin_amdgcn_update_dpp(                      \
        (int)lo_, (int)lo_, (ctrl), 0xf, 0xf, false);                       \
    const u32 nhi_ = (u32)__builtin_amdgcn_update_dpp(                      \
        (int)hi_, (int)hi_, (ctrl), 0xf, 0xf, false);                       \
    const u64 ok_ = ((u64)nhi_ << 32) | nlo_;                               \
    if (ok_ > (k)) (k) = ok_;                                               \
  }

// L1-bypass load served by the XCD-local L2 (sc0 == GLC on gfx940+).
__device__ __forceinline__ u64 ld_sc0(const u64* p) {
  u64 v;
  asm volatile("global_load_dwordx2 %0, %1, off sc0\n\t"
               "s_waitcnt vmcnt(0)"
               : "=v"(v) : "v"(p) : "memory");
  return v;
}

__global__ __launch_bounds__(T_)
__attribute__((amdgpu_waves_per_eu(2, 2)))
void fps_kernel(
    const float* __restrict__ xyz,   // (B, N, 3)
    float* __restrict__ out,
    u64* __restrict__ partsA,        // (B_*S_, 4) agent slots, pre-zeroed
    u64* __restrict__ partsL,        // (B_*S_, 16) local slots (128B rows), pre-zeroed
    u64* __restrict__ disc)          // (NBLK) xcd discovery slots, pre-zeroed
{
#pragma clang fp contract(off)
  const int blk  = blockIdx.x;
  const int t    = threadIdx.x;
  const int lane = t & 63;
  const int w    = t >> 6;

  float* out_xyz = out;
  float* out_idx = out + (size_t)B_*S_*3 + (size_t)B_*C_*S_;

  __shared__ u64 red[2][W_];         // per-wave winner keys
  __shared__ u64 winq[2];            // block winner broadcast

  // ---- one-time XCD discovery -> deterministic (batch, quarter) assignment.
  u32 xcc;
  asm volatile("s_getreg_b32 %0, hwreg(HW_REG_XCC_ID)" : "=s"(xcc));
  if (t == 0) {
    __hip_atomic_store(&disc[blk], (u64)(xcc + 1), __ATOMIC_RELAXED,
                       __HIP_MEMORY_SCOPE_AGENT);
  }
  u64 dv;
  do {
    dv = __hip_atomic_load(&disc[lane & 31], __ATOMIC_RELAXED,
                           __HIP_MEMORY_SCOPE_AGENT);
  } while (__ballot(dv != 0) != ~0ull);        // all 32 published first
  const int xl = (int)dv - 1;                  // xcd of block (lane&31)
  const u64 M32 = 0xFFFFFFFFull;
  const int idx = lane & 31;
  const int Pn  = (int)__popcll(__ballot(xl < (int)xcc) & M32);
  const int Cn  = (int)__popcll(__ballot(xl == (int)xcc) & M32);
  const int rin = (int)__popcll(__ballot(xl == (int)xcc && idx < blk) & M32);
  const int rank  = Pn + rin;                  // unique in [0, NBLK)
  const int batch = rank >> 2;                 // my batch
  const int mq    = rank & 3;                  // my quarter 0..3
  const bool fast_ok = (4*batch >= Pn) && (4*batch + 4 <= Pn + Cn);  // all 4 same xcd

  const float* xb = xyz + (size_t)batch * N_ * 3;
  const int base = mq * QTR;

  // Quarter-batch coords + min-dists fully in arch VGPRs (48 + 16 floats).
  // Pair k covers ordinals j = 2k, 2k+1; point g = base + j*T_ + t
  // (ascending j -> per-thread first-max scan == smallest global index).
  f2v XR[PRS], YR[PRS], ZR[PRS], Dr[PRS];
  #pragma unroll
  for (int k = 0; k < PRS; ++k) {
    const int g0 = base + (2*k)   * T_ + t;
    const int g1 = base + (2*k+1) * T_ + t;
    XR[k] = (f2v){xb[g0*3+0], xb[g1*3+0]};
    YR[k] = (f2v){xb[g0*3+1], xb[g1*3+1]};
    ZR[k] = (f2v){xb[g0*3+2], xb[g1*3+2]};
    Dr[k] = (f2v){1e10f, 1e10f};
  }
  #pragma unroll
  for (int k = 0; k < PRS; ++k) {
    asm volatile("" : "+v"(XR[k]), "+v"(YR[k]), "+v"(ZR[k]));  // no remat
  }

  bool fastm = fast_ok;              // wave-0 sticky; demote on local timeout
  int cur = 0;
  for (int s = 0; s < S_; ++s) {
    const int cu = __builtin_amdgcn_readfirstlane(cur);   // uniform -> scalar loads
    const float cx = xb[cu*3+0];
    const float cy = xb[cu*3+1];
    const float cz = xb[cu*3+2];
    if (mq == 0 && t == 0) {
      out_idx[(size_t)batch*S_ + s] = (float)cu;
      float* o = out_xyz + ((size_t)batch*S_ + s)*3;
      o[0] = cx; o[1] = cy; o[2] = cz;
    }
    const f2v c2x = (f2v){cx, cx};
    const f2v c2y = (f2v){cy, cy};
    const f2v c2z = (f2v){cz, cz};

    // Exact IEEE ((dx*dx + dy*dy) + dz*dz), no contraction, packed pairs.
    float bv = -1.0f;
    int   bq = 0;
    f2v nw01 = (f2v){0.f, 0.f}, nw23 = (f2v){0.f, 0.f};

    #define UQ(qc)                                                         \
      {                                                                    \
        const f2v dx0 = XR[2*(qc)]   - c2x;                                \
        const f2v dy0 = YR[2*(qc)]   - c2y;                                \
        const f2v dz0 = ZR[2*(qc)]   - c2z;                                \
        const f2v d0  = (dx0*dx0 + dy0*dy0) + dz0*dz0;                     \
        const f2v dx1 = XR[2*(qc)+1] - c2x;                                \
        const f2v dy1 = YR[2*(qc)+1] - c2y;                                \
        const f2v dz1 = ZR[2*(qc)+1] - c2z;                                \
        const f2v d1  = (dx1*dx1 + dy1*dy1) + dz1*dz1;                     \
        const f2v nd0 = __builtin_elementwise_min(Dr[2*(qc)],   d0);       \
        const f2v nd1 = __builtin_elementwise_min(Dr[2*(qc)+1], d1);       \
        Dr[2*(qc)]   = nd0;                                                \
        Dr[2*(qc)+1] = nd1;                                                \
        const f2v qm2 = __builtin_elementwise_max(nd0, nd1);               \
        const float qm = fmaxf(qm2.x, qm2.y);                              \
        if (qm > bv) { bv = qm; bq = (qc); nw01 = nd0; nw23 = nd1; }       \
      }
    #pragma unroll
    for (int q = 0; q < NQ; ++q) { UQ(q); }
    #undef UQ

    // Element within winning quad (fmax returns operands bitwise ->
    // equality holds). Descending priority == first (smallest) element.
    int e = 3;
    if (nw23.x == bv) e = 2;
    if (nw01.y == bv) e = 1;
    if (nw01.x == bv) e = 0;
    const int bj = (bq << 2) + e;          // per-thread ordinal 0..15
    const int bg = base + (bj << 9) + t;   // global point index (T_ == 512)

    // Wave DPP max on key = (bits(bv)<<32) | ~bg: (max dist, min idx).
    u64 key = ((u64)__float_as_uint(bv) << 32) | (u32)(~bg);
    U64_DPP_MAX(key, 0x111);
    U64_DPP_MAX(key, 0x112);
    U64_DPP_MAX(key, 0x114);
    U64_DPP_MAX(key, 0x118);
    U64_DPP_MAX(key, 0x142);
    U64_DPP_MAX(key, 0x143);
    if (lane == 63) red[s & 1][w] = key;
    __syncthreads();                       // barrier 1

    u64* rowA = partsA + ((size_t)(batch * S_ + s) << 2);
    u64* rowL = partsL + ((size_t)(batch * S_ + s) << 4);   // 128 B rows

    if (w < 2) {
      // Block key from the 8 per-wave keys (3-level DPP, lane 7 has max).
      u64 k = red[s & 1][lane & (W_ - 1)];
      U64_DPP_MAX(k, 0x111);
      U64_DPP_MAX(k, 0x112);
      U64_DPP_MAX(k, 0x114);
      const u32 klo = (u32)__builtin_amdgcn_readlane((int)(u32)k, 7);
      const u32 khi = (u32)__builtin_amdgcn_readlane((int)(k >> 32), 7);
      const u64 kblk = ((u64)khi << 32) | klo;

      if (w == 1) {
        // Publisher wave: both transports, every step (fallback always live).
        if (lane == 0) {
          if (fast_ok) {
            __hip_atomic_store(&rowL[mq], kblk, __ATOMIC_RELAXED,
                               __HIP_MEMORY_SCOPE_WORKGROUP);  // plain -> local L2
          }
          __hip_atomic_store(&rowA[mq], kblk, __ATOMIC_RELAXED,
                             __HIP_MEMORY_SCOPE_AGENT);
        }
      } else {
        // Poller wave (no stores -> vmcnt is pure load RT). Lanes 0-3
        // cover the 4 slots; own slot substituted from registers.
        u64 ko = 0;
        bool got = false;
        if (fastm) {
          const int tries = (s == 0) ? 512 : 32;
          for (int i = 0; i < tries; ++i) {
            u64 vv = ld_sc0(rowL + (lane & 3));
            if ((lane & 3) == mq) vv = kblk;
            ko = vv;
            if (__ballot(ko != 0) == ~0ull) { got = true; break; }
          }
          if (!got) fastm = false;         // sticky demotion
        }
        if (!got) {
          do {
            ko = __hip_atomic_load(&rowA[lane & 3], __ATOMIC_RELAXED,
                                   __HIP_MEMORY_SCOPE_AGENT);
            if ((lane & 3) == mq) ko = kblk;
          } while (__ballot(ko != 0) != ~0ull);
        }
        u64 kw = (ko > kblk) ? ko : kblk;
        U64_DPP_MAX(kw, 0x111);            // lane 3 = max of slots 0..3
        U64_DPP_MAX(kw, 0x112);
        const u32 wlo = (u32)__builtin_amdgcn_readlane((int)(u32)kw, 3);
        const u32 whi = (u32)__builtin_amdgcn_readlane((int)(kw >> 32), 3);
        if (lane == 0) winq[s & 1] = ((u64)whi << 32) | wlo;
      }
    }
    __syncthreads();                       // barrier 2
    cur = (int)(u32)(~(u32)winq[s & 1]);   // decode winner index
  }
}

__global__ void gather_fea_kernel(
    const float* __restrict__ feat,   // (B, C, N)
    const float* __restrict__ idxf,   // (B, S) float indices (in d_out)
    float* __restrict__ out_fea)      // (B, C, S)
{
  const int t = blockIdx.x * blockDim.x + threadIdx.x;
  if (t >= B_ * C_ * S_) return;
  const int s  = t & (S_ - 1);
  const int bc = t >> 10;           // S_ == 1024
  const int c  = bc % C_;
  const int b  = bc / C_;
  const int idx = (int)idxf[(size_t)b * S_ + s];
  out_fea[t] = feat[((size_t)b * C_ + c) * (size_t)N_ + idx];
}

extern "C" void kernel_launch(void* const* d_in, const int* in_sizes, int n_in,
                              void* d_out, int out_size, void* d_ws, size_t ws_size,
                              hipStream_t stream) {
  const float* xyz  = (const float*)d_in[0];   // (B,N,3)
  const float* feat = (const float*)d_in[1];   // (B,C,N)
  float* out = (float*)d_out;

  float* out_fea = out + (size_t)B_ * S_ * 3;
  float* out_idx = out + (size_t)B_ * S_ * 3 + (size_t)B_ * C_ * S_;
  (void)d_ws; (void)ws_size; (void)in_sizes; (void)n_in; (void)out_size;

  // Slot scratch in the out_fea region (3 MB): partsA (256 KB, agent-only
  // traffic) | partsL (1 MB, 128B rows, local-only traffic) | disc (256 B).
  // Fully overwritten by gather_fea_kernel afterwards. Memset zeros are
  // flushed to the coherence point before fps starts (stream order).
  u64* partsA = (u64*)out_fea;
  u64* partsL = partsA + (size_t)B_ * S_ * 4;
  u64* disc   = partsL + (size_t)B_ * S_ * 16;
  hipMemsetAsync(partsA, 0,
                 ((size_t)B_ * S_ * 20 + NBLK) * sizeof(u64), stream);

  fps_kernel<<<NBLK, T_, 0, stream>>>(xyz, out, partsA, partsL, disc);

  const int total = B_ * C_ * S_;
  gather_fea_kernel<<<(total + 255) / 256, 256, 0, stream>>>(feat, out_idx, out_fea);
}